// Round 14
// baseline (74.436 us; speedup 1.0000x reference)
//
#include <hip/hip_runtime.h>
#include <hip/hip_bf16.h>

typedef unsigned short u16;
typedef __attribute__((ext_vector_type(8))) unsigned short ushort8;
typedef __attribute__((ext_vector_type(8))) __bf16 bf16x8;
typedef __attribute__((ext_vector_type(4))) float f32x4;

// N=16, L=4096, IN_DIM=32, D=E=512
#define NB 16
#define SEQ 4096
#define DIM 512
#define INDIM 32
#define NTOK (NB * SEQ)    // 65536
#define WBM 256            // tokens per k_w tile
#define NTILE (NTOK / WBM) // 256 (16 per batch)

static __device__ __forceinline__ u16 f2bf(float f) {
    union { float f; unsigned u; } x; x.f = f;
    unsigned r = (x.u + 0x7FFFu + ((x.u >> 16) & 1u)) >> 16;
    return (u16)r;
}
static __device__ __forceinline__ float bf2f(u16 b) {
    union { unsigned u; float f; } x; x.u = ((unsigned)b) << 16;
    return x.f;
}

__device__ __forceinline__ float dot32(const float* __restrict__ w, const float* v) {
    const float4* a = (const float4*)w;
    float acc = 0.f;
    #pragma unroll
    for (int i = 0; i < 8; ++i) {
        float4 p = a[i];
        acc += p.x * v[4*i] + p.y * v[4*i+1] + p.z * v[4*i+2] + p.w * v[4*i+3];
    }
    return acc;
}

// ===================== k_p1: input-only precomputes (r13-verified) =====================
// grid 704:
//   [0,384):   mats wq/wk/wv -> wq2/bq2, wk2b/bk2, wv2/wvb. 4 rows/block, float4 w_in loads.
//   [384,512): wff1 rows -> wf1x, wf1c, wg1, wb1, bb. 4 rows/block.
//   [512,704): bf16 transposes MT[k][d]: m=0 wo, m=1 wff1*g1, m=2 wff2 (64 tiles each)
__global__ __launch_bounds__(256) void k_p1(
    const float* __restrict__ x,
    const float* __restrict__ w_in, const float* __restrict__ b_in,
    const float* __restrict__ wq, const float* __restrict__ bq,
    const float* __restrict__ wk, const float* __restrict__ bk,
    const float* __restrict__ wv, const float* __restrict__ bv,
    const float* __restrict__ wo, const float* __restrict__ bo,
    const float* __restrict__ g1, const float* __restrict__ b1,
    const float* __restrict__ wff1, const float* __restrict__ wff2,
    float* __restrict__ wq2, float* __restrict__ bq2,
    u16* __restrict__ wk2b, float* __restrict__ bk2,
    float* __restrict__ wv2, float* __restrict__ wvb,
    float* __restrict__ wf1x, float* __restrict__ wf1c,
    float* __restrict__ wg1, float* __restrict__ wb1, float* __restrict__ bb,
    u16* __restrict__ woT, u16* __restrict__ wff1g1T, u16* __restrict__ wff2T) {
    __shared__ float smem[64 * 65];   // 16.6 KiB, reused per segment
    int bid = blockIdx.x, tid = threadIdx.x;

    if (bid < 384) {
        int mat = bid >> 7, e0 = (bid & 127) * 4;
        int row = tid >> 6, kc = (tid >> 3) & 7, j4 = tid & 7;
        const float* A = (mat == 0 ? wq : (mat == 1 ? wk : wv))
                       + (long)(e0 + row) * DIM + kc * 64;
        const float* wbase = w_in + (kc * 64) * INDIM + j4 * 4;
        const float* bbase = b_in + kc * 64;
        float a0 = 0.f, a1 = 0.f, a2 = 0.f, a3 = 0.f, accb = 0.f;
        #pragma unroll 8
        for (int i = 0; i < 64; ++i) {
            float a = A[i];
            float4 w4 = *(const float4*)(wbase + i * INDIM);
            a0 += a * w4.x; a1 += a * w4.y; a2 += a * w4.z; a3 += a * w4.w;
            accb += a * bbase[i];
        }
        float* red  = smem;              // [4][8][33]
        float* redb = smem + 4 * 8 * 33; // [4][8]
        int rb = (row * 8 + kc) * 33 + j4 * 4;
        red[rb + 0] = a0; red[rb + 1] = a1; red[rb + 2] = a2; red[rb + 3] = a3;
        if (j4 == 0) redb[row * 8 + kc] = accb;
        __syncthreads();
        if (tid < 128) {
            int r = tid >> 5, j = tid & 31;
            float s = 0.f;
            #pragma unroll
            for (int k2 = 0; k2 < 8; ++k2) s += red[(r * 8 + k2) * 33 + j];
            int e = e0 + r;
            if (mat == 0) wq2[e * INDIM + j] = s;
            else if (mat == 1) wk2b[e * INDIM + j] = f2bf(s);
            else wv2[e * INDIM + j] = s;
        } else if (tid < 132) {
            int r = tid - 128;
            float s = 0.f;
            #pragma unroll
            for (int k2 = 0; k2 < 8; ++k2) s += redb[r * 8 + k2];
            int e = e0 + r;
            if (mat == 0) bq2[e] = bq[e] + s;
            else if (mat == 1) bk2[e] = bk[e] + s;
            else wvb[e] = s + bv[e];
        }
    } else if (bid < 512) {
        int e0 = (bid - 384) * 4;
        int row = tid >> 6, kc = (tid >> 3) & 7, j4 = tid & 7;
        const float* A = wff1 + (long)(e0 + row) * DIM + kc * 64;
        const float* wbase = w_in + (kc * 64) * INDIM + j4 * 4;
        int dbase = kc * 64;
        float a0 = 0.f, a1 = 0.f, a2 = 0.f, a3 = 0.f;
        float accc = 0.f, accg = 0.f, accb1 = 0.f;
        #pragma unroll 4
        for (int i = 0; i < 64; ++i) {
            int d = dbase + i;
            float a = A[i], g = g1[d], ag = a * g;
            float4 w4 = *(const float4*)(wbase + i * INDIM);
            a0 += ag * w4.x; a1 += ag * w4.y; a2 += ag * w4.z; a3 += ag * w4.w;
            accc += ag * (b_in[d] + bo[d]);
            accg += ag;
            accb1 += a * b1[d];
        }
        float* red  = smem;                    // [4][8][33]
        float* red2 = smem + 4 * 8 * 33;       // [4][8][3]
        int rb = (row * 8 + kc) * 33 + j4 * 4;
        red[rb + 0] = a0; red[rb + 1] = a1; red[rb + 2] = a2; red[rb + 3] = a3;
        if (j4 == 0) {
            int b2 = (row * 8 + kc) * 3;
            red2[b2 + 0] = accc; red2[b2 + 1] = accg; red2[b2 + 2] = accb1;
        }
        __syncthreads();
        if (tid < 128) {
            int r = tid >> 5, j = tid & 31;
            float s = 0.f;
            #pragma unroll
            for (int k2 = 0; k2 < 8; ++k2) s += red[(r * 8 + k2) * 33 + j];
            wf1x[(e0 + r) * INDIM + j] = s;
        } else if (tid < 132) {
            int r = tid - 128;
            float sc = 0.f, sg = 0.f, sb = 0.f;
            #pragma unroll
            for (int k2 = 0; k2 < 8; ++k2) {
                int b2 = (r * 8 + k2) * 3;
                sc += red2[b2 + 0]; sg += red2[b2 + 1]; sb += red2[b2 + 2];
            }
            int e = e0 + r;
            wf1c[e] = sc; wg1[e] = sg; wb1[e] = sb;
            bb[e] = b_in[e] + bo[e];
        }
    } else {
        // transpose+cvt: MT[k][d] = bf16(M[d][k] * (m==1 ? g1[k] : 1)); 64x64 tiles
        int t = bid - 512;             // 0..191
        int m = t >> 6;                // 0 wo, 1 wff1*g1, 2 wff2
        int tt = t & 63;
        int r = tt >> 3, c = tt & 7;   // d-tile, k-tile
        const float* M = (m == 0) ? wo : (m == 1 ? wff1 : wff2);
        u16* MT = (m == 0) ? woT : (m == 1 ? wff1g1T : wff2T);
        float* tile = smem;            // [64][65]
        int rr = tid >> 2, cc = (tid & 3) * 16;
        const float* src = M + (long)(r * 64 + rr) * DIM + c * 64 + cc;
        #pragma unroll
        for (int i = 0; i < 4; ++i) {
            float4 v = *(const float4*)(src + i * 4);
            tile[rr * 65 + cc + i * 4 + 0] = v.x;
            tile[rr * 65 + cc + i * 4 + 1] = v.y;
            tile[rr * 65 + cc + i * 4 + 2] = v.z;
            tile[rr * 65 + cc + i * 4 + 3] = v.w;
        }
        __syncthreads();
        int orr = tid >> 2, occ = (tid & 3) * 16;   // k-local, d-chunk
        float gk = (m == 1) ? g1[c * 64 + orr] : 1.f;
        u16 ob[16];
        #pragma unroll
        for (int i = 0; i < 16; ++i) ob[i] = f2bf(tile[(occ + i) * 65 + orr] * gk);
        u16* dst = MT + (long)(c * 64 + orr) * DIM + r * 64 + occ;
        *(ushort8*)dst = *(ushort8*)ob;
        *(ushort8*)(dst + 8) = *(ushort8*)(ob + 8);
    }
}

// ===================== k_w: 256 token tiles of 256 (q0 in-block from wq2) =====================
__global__ __launch_bounds__(256) void k_w(
    const float* __restrict__ x,
    const float* __restrict__ wq2, const float* __restrict__ bq2,
    const u16* __restrict__ wk2b, const float* __restrict__ bk2,
    float* __restrict__ xup, float* __restrict__ zdp) {
    __shared__ u16 sB[DIM * 40];       // 40960 B
    __shared__ float s_q0[DIM];        // 2048
    __shared__ float sw[WBM];          // 1024
    __shared__ float sxu8[8][32];      // 1024
    __shared__ float szz[8];           // 32
    __shared__ float sx0[INDIM];       // 128
    int tid = threadIdx.x;
    int tt = blockIdx.x;
    int lane = tid & 63, wid = tid >> 6;
    long tbase = (long)tt * WBM;
    int batch = (int)(tbase >> 12);

    #pragma unroll
    for (int pp = 0; pp < 8; ++pp) {
        int f = (pp * 256 + tid) * 8;
        int row = f >> 5, colc = f & 31;
        ushort8 v = *(const ushort8*)(wk2b + f);
        *(ushort8*)(sB + row * 40 + colc) = v;
    }
    if (tid < INDIM) sx0[tid] = x[(long)batch * SEQ * INDIM + tid];
    __syncthreads();
    #pragma unroll
    for (int rep = 0; rep < 2; ++rep) {
        int e = tid + rep * 256;
        float a = bq2[e] + dot32(wq2 + e * INDIM, sx0);
        s_q0[e] = (a > 0.f) ? (a + 1.f) : __expf(a);
    }

    int col = lane & 15;
    int koff = (lane >> 4) * 8;
    // 4 A-fragments per wave: rows wid*64 + mi*16 + col
    bf16x8 fa[4];
    #pragma unroll
    for (int mi = 0; mi < 4; ++mi) {
        const float* xr = x + (tbase + wid * 64 + mi * 16 + col) * INDIM + koff;
        float4 a0 = *(const float4*)(xr);
        float4 a1 = *(const float4*)(xr + 4);
        u16 tmp[8] = { f2bf(a0.x), f2bf(a0.y), f2bf(a0.z), f2bf(a0.w),
                       f2bf(a1.x), f2bf(a1.y), f2bf(a1.z), f2bf(a1.w) };
        fa[mi] = *(bf16x8*)tmp;
    }
    __syncthreads();

    float q0v[32], bkv[32];
    #pragma unroll
    for (int ni = 0; ni < 32; ++ni) {
        q0v[ni] = s_q0[ni * 16 + col];
        bkv[ni] = bk2[ni * 16 + col];
    }

    f32x4 zero = {0.f, 0.f, 0.f, 0.f};
    float wpart[4][4] = {};
    #pragma unroll
    for (int nc = 0; nc < 4; ++nc) {
        bf16x8 fb[8];
        #pragma unroll
        for (int nj = 0; nj < 8; ++nj) {
            int row = (nc * 8 + nj) * 16 + col;
            fb[nj] = *(const bf16x8*)(sB + row * 40 + koff);
        }
        #pragma unroll
        for (int mi = 0; mi < 4; ++mi) {
            #pragma unroll
            for (int nj = 0; nj < 8; ++nj) {
                f32x4 acc = __builtin_amdgcn_mfma_f32_16x16x32_bf16(fa[mi], fb[nj], zero, 0, 0, 0);
                int ni = nc * 8 + nj;
                #pragma unroll
                for (int r = 0; r < 4; ++r) {
                    float v = acc[r] + bkv[ni];
                    v = (v > 0.f) ? (v + 1.f) : __expf(v);
                    wpart[mi][r] += v * q0v[ni];
                }
            }
        }
    }
    #pragma unroll
    for (int mi = 0; mi < 4; ++mi) {
        #pragma unroll
        for (int r = 0; r < 4; ++r) {
            float s = wpart[mi][r];
            s += __shfl_xor(s, 1, 64); s += __shfl_xor(s, 2, 64);
            s += __shfl_xor(s, 4, 64); s += __shfl_xor(s, 8, 64);
            if (col == 0) sw[wid * 64 + mi * 16 + (lane >> 4) * 4 + r] = s;
        }
    }
    __syncthreads();
    {
        int j = tid & 31, g = tid >> 5;
        float a = 0.f, z = 0.f;
        for (int tl = g; tl < WBM; tl += 8) {
            float wv_ = sw[tl];
            a += wv_ * x[(tbase + tl) * INDIM + j];
            if (j == 0) z += wv_;
        }
        sxu8[g][j] = a;
        if (j == 0) szz[g] = z;
    }
    __syncthreads();
    if (tid < 32) {
        float a = 0.f;
        #pragma unroll
        for (int g = 0; g < 8; ++g) a += sxu8[g][tid];
        xup[tt * INDIM + tid] = a;
    } else if (tid == 32) {
        float z = 0.f;
        #pragma unroll
        for (int g = 0; g < 8; ++g) z += szz[g];
        zdp[tt] = z;
    }
}

// ===================== k_final: 3 coalesced GEMVs + LNs (r10/r13-verified) =====================
__device__ __forceinline__ void reduce2_512(float a, float b, int tid, float* l16,
                                            float& oa, float& ob) {
    #pragma unroll
    for (int off = 1; off < 64; off <<= 1) {
        a += __shfl_xor(a, off, 64);
        b += __shfl_xor(b, off, 64);
    }
    int w = tid >> 6;
    if ((tid & 63) == 0) { l16[w] = a; l16[8 + w] = b; }
    __syncthreads();
    float ra = 0.f, rb = 0.f;
    #pragma unroll
    for (int i = 0; i < 8; ++i) { ra += l16[i]; rb += l16[8 + i]; }
    oa = ra; ob = rb;
    __syncthreads();
}

__device__ __forceinline__ float gemv512(const u16* __restrict__ MT,
                                         const float* __restrict__ vec,
                                         float* __restrict__ spart,
                                         int tid, int d) {
    int kc = tid >> 6, dg = tid & 63;
    float ps[8] = {};
    const u16* base = MT + (long)(kc * 64) * DIM + dg * 8;
    #pragma unroll 8
    for (int k8 = 0; k8 < 64; ++k8) {
        ushort8 w8 = *(const ushort8*)(base + (long)k8 * DIM);
        float fk = vec[kc * 64 + k8];
        #pragma unroll
        for (int j = 0; j < 8; ++j) ps[j] += bf2f(w8[j]) * fk;
    }
    #pragma unroll
    for (int j = 0; j < 8; ++j) spart[kc * DIM + dg * 8 + j] = ps[j];
    __syncthreads();
    float acc = 0.f;
    #pragma unroll
    for (int i = 0; i < 8; ++i) acc += spart[i * DIM + d];
    return acc;
}

__global__ __launch_bounds__(512) void k_final(
    const float* __restrict__ x, const float* __restrict__ w_in,
    const float* __restrict__ wv2, const float* __restrict__ wvb,
    const float* __restrict__ bb,
    const float* __restrict__ wf1x, const float* __restrict__ wf1c,
    const float* __restrict__ wg1, const float* __restrict__ wb1,
    const float* __restrict__ g1, const float* __restrict__ b1,
    const float* __restrict__ bff1, const float* __restrict__ bff2,
    const u16* __restrict__ woT, const u16* __restrict__ wff1g1T,
    const u16* __restrict__ wff2T,
    const float* __restrict__ g2, const float* __restrict__ b2,
    const float* __restrict__ gf, const float* __restrict__ bfv,
    const float* __restrict__ wfc, const float* __restrict__ bfc,
    const float* __restrict__ xup, const float* __restrict__ zdp,
    float* __restrict__ out) {
    __shared__ float sx0[INDIM], sxu[INDIM];
    __shared__ float sv[DIM];
    __shared__ float sf[DIM];
    __shared__ float spart[8 * DIM];   // 16 KiB
    __shared__ float l16[16];
    __shared__ float szd;
    int n = blockIdx.x, tid = threadIdx.x, d = tid;
    if (tid < INDIM) {
        float a = 0.f;
        #pragma unroll
        for (int slot = 0; slot < 16; ++slot)
            a += xup[(n * 16 + slot) * INDIM + tid];
        sxu[tid] = a;
        sx0[tid] = x[(long)n * SEQ * INDIM + tid];
    } else if (tid == 32) {
        float z = 0.f;
        #pragma unroll
        for (int slot = 0; slot < 16; ++slot) z += zdp[n * 16 + slot];
        szd = z;
    }
    __syncthreads();
    float zd = szd;
    float Z = 1.f / (zd + 1e-6f);
    float zz = zd * Z;

    // u2 = wv2 @ xu ; GEMV-A input v = Z*u2 + zz*wvb
    float u2d = dot32(wv2 + d * INDIM, sxu);
    sv[d] = Z * u2d + zz * wvb[d];
    __syncthreads();

    // o = wo @ v  (coalesced woT)
    float o_d = gemv512(woT, sv, spart, tid, d);

    // r = bb + w_in@x0 + o ; LN1  (reduce's syncs also fence spart reuse)
    float rd = bb[d] + dot32(w_in + d * INDIM, sx0) + o_d;
    sv[d] = o_d;   // GEMV-B input (g1 folded into wff1g1T)
    float sum, sumsq;
    reduce2_512(rd, rd * rd, tid, l16, sum, sumsq);
    float mu1 = sum * (1.f / DIM);
    float s1 = rsqrtf(sumsq * (1.f / DIM) - mu1 * mu1 + 1e-5f);
    float r1 = (rd - mu1) * s1 * g1[d] + b1[d];

    // G = wf1x@x0 + (wff1*g1)@o + wf1c ; fpre ; f = relu
    float W_d = gemv512(wff1g1T, sv, spart, tid, d);
    float G = dot32(wf1x + d * INDIM, sx0) + W_d + wf1c[d];
    float fp = s1 * (G - mu1 * wg1[d]) + wb1[d] + bff1[d];
    __syncthreads();            // fence spart reads before GEMV-C writes
    sf[d] = fmaxf(fp, 0.f);
    __syncthreads();

    // y = r1 + wff2@f + bff2
    float yacc = gemv512(wff2T, sf, spart, tid, d);
    float y = r1 + bff2[d] + yacc;

    reduce2_512(y, y * y, tid, l16, sum, sumsq);
    float mu2 = sum * (1.f / DIM);
    float inv2 = rsqrtf(sumsq * (1.f / DIM) - mu2 * mu2 + 1e-5f);
    float h2 = (y - mu2) * inv2 * g2[d] + b2[d];

    reduce2_512(h2, h2 * h2, tid, l16, sum, sumsq);
    float mu3 = sum * (1.f / DIM);
    float inv3 = rsqrtf(sumsq * (1.f / DIM) - mu3 * mu3 + 1e-5f);
    float h3 = (h2 - mu3) * inv3 * gf[d] + bfv[d];

    float pfc = wfc[d] * h3;
    float dummy;
    reduce2_512(pfc, 0.f, tid, l16, sum, dummy);
    if (tid == 0) out[n] = sum + bfc[0];
}

extern "C" void kernel_launch(void* const* d_in, const int* in_sizes, int n_in,
                              void* d_out, int out_size, void* d_ws, size_t ws_size,
                              hipStream_t stream) {
    const float* x    = (const float*)d_in[0];
    const float* w_in = (const float*)d_in[1];
    const float* b_in = (const float*)d_in[2];
    const float* wq   = (const float*)d_in[3];
    const float* bq   = (const float*)d_in[4];
    const float* wk   = (const float*)d_in[5];
    const float* bk   = (const float*)d_in[6];
    const float* wv   = (const float*)d_in[7];
    const float* bv   = (const float*)d_in[8];
    const float* wo   = (const float*)d_in[9];
    const float* bo   = (const float*)d_in[10];
    const float* g1   = (const float*)d_in[11];
    const float* b1   = (const float*)d_in[12];
    const float* wff1 = (const float*)d_in[13];
    const float* bff1 = (const float*)d_in[14];
    const float* wff2 = (const float*)d_in[15];
    const float* bff2 = (const float*)d_in[16];
    const float* g2   = (const float*)d_in[17];
    const float* b2   = (const float*)d_in[18];
    const float* gf   = (const float*)d_in[19];
    const float* bf   = (const float*)d_in[20];
    const float* wfc  = (const float*)d_in[21];
    const float* bfc  = (const float*)d_in[22];

    char* ws = (char*)d_ws;
    float* wq2     = (float*)(ws + 0);         // 64 KiB
    float* bq2     = (float*)(ws + 65536);     // 2 KiB
    u16*   wk2b    = (u16*)  (ws + 67584);     // 32 KiB
    float* bk2     = (float*)(ws + 100352);    // 2 KiB
    float* wv2     = (float*)(ws + 102400);    // 64 KiB
    float* wvb     = (float*)(ws + 167936);    // 2 KiB
    float* bb      = (float*)(ws + 169984);    // 2 KiB
    float* wf1x    = (float*)(ws + 172032);    // 64 KiB
    float* wf1c    = (float*)(ws + 237568);    // 2 KiB
    float* wg1     = (float*)(ws + 239616);    // 2 KiB
    float* wb1     = (float*)(ws + 241664);    // 2 KiB
    u16*   woT     = (u16*)  (ws + 243712);    // 512 KiB
    u16*   wff1g1T = (u16*)  (ws + 767872);    // 512 KiB
    u16*   wff2T   = (u16*)  (ws + 1292160);   // 512 KiB
    float* xup     = (float*)(ws + 1816448);   // 32 KiB  [256][32]
    float* zdp     = (float*)(ws + 1849344);   // 1 KiB   [256]

    k_p1<<<704, 256, 0, stream>>>(x, w_in, b_in, wq, bq, wk, bk, wv, bv, wo, bo,
                                  g1, b1, wff1, wff2,
                                  wq2, bq2, wk2b, bk2, wv2, wvb,
                                  wf1x, wf1c, wg1, wb1, bb,
                                  woT, wff1g1T, wff2T);
    k_w<<<NTILE, 256, 0, stream>>>(x, wq2, bq2, wk2b, bk2, xup, zdp);
    k_final<<<NB, 512, 0, stream>>>(x, w_in, wv2, wvb, bb, wf1x, wf1c, wg1, wb1,
                                    g1, b1, bff1, bff2, woT, wff1g1T, wff2T,
                                    g2, b2, gf, bf, wfc, bfc, xup, zdp,
                                    (float*)d_out);
}

// Round 15
// 66.931 us; speedup vs baseline: 1.1121x; 1.1121x over previous
//
#include <hip/hip_runtime.h>
#include <hip/hip_bf16.h>

typedef unsigned short u16;
typedef __attribute__((ext_vector_type(8))) unsigned short ushort8;
typedef __attribute__((ext_vector_type(8))) __bf16 bf16x8;
typedef __attribute__((ext_vector_type(4))) float f32x4;

// N=16, L=4096, IN_DIM=32, D=E=512
#define NB 16
#define SEQ 4096
#define DIM 512
#define INDIM 32
#define NTOK (NB * SEQ)    // 65536
#define WBM 128            // tokens per k_w tile
#define NTILE (NTOK / WBM) // 512

static __device__ __forceinline__ u16 f2bf(float f) {
    union { float f; unsigned u; } x; x.f = f;
    unsigned r = (x.u + 0x7FFFu + ((x.u >> 16) & 1u)) >> 16;
    return (u16)r;
}
static __device__ __forceinline__ float bf2f(u16 b) {
    union { unsigned u; float f; } x; x.u = ((unsigned)b) << 16;
    return x.f;
}

__device__ __forceinline__ float dot32(const float* __restrict__ w, const float* v) {
    const float4* a = (const float4*)w;
    float acc = 0.f;
    #pragma unroll
    for (int i = 0; i < 8; ++i) {
        float4 p = a[i];
        acc += p.x * v[4*i] + p.y * v[4*i+1] + p.z * v[4*i+2] + p.w * v[4*i+3];
    }
    return acc;
}

// ===================== k_p1: input-only precomputes (r13-verified) =====================
__global__ __launch_bounds__(256) void k_p1(
    const float* __restrict__ x,
    const float* __restrict__ w_in, const float* __restrict__ b_in,
    const float* __restrict__ wq, const float* __restrict__ bq,
    const float* __restrict__ wk, const float* __restrict__ bk,
    const float* __restrict__ wv, const float* __restrict__ bv,
    const float* __restrict__ wo, const float* __restrict__ bo,
    const float* __restrict__ g1, const float* __restrict__ b1,
    const float* __restrict__ wff1, const float* __restrict__ wff2,
    float* __restrict__ wq2, float* __restrict__ bq2,
    u16* __restrict__ wk2b, float* __restrict__ bk2,
    float* __restrict__ wv2, float* __restrict__ wvb,
    float* __restrict__ wf1x, float* __restrict__ wf1c,
    float* __restrict__ wg1, float* __restrict__ wb1, float* __restrict__ bb,
    u16* __restrict__ woT, u16* __restrict__ wff1g1T, u16* __restrict__ wff2T) {
    __shared__ float smem[64 * 65];   // 16.6 KiB, reused per segment
    int bid = blockIdx.x, tid = threadIdx.x;

    if (bid < 384) {
        int mat = bid >> 7, e0 = (bid & 127) * 4;
        int row = tid >> 6, kc = (tid >> 3) & 7, j4 = tid & 7;
        const float* A = (mat == 0 ? wq : (mat == 1 ? wk : wv))
                       + (long)(e0 + row) * DIM + kc * 64;
        const float* wbase = w_in + (kc * 64) * INDIM + j4 * 4;
        const float* bbase = b_in + kc * 64;
        float a0 = 0.f, a1 = 0.f, a2 = 0.f, a3 = 0.f, accb = 0.f;
        #pragma unroll 8
        for (int i = 0; i < 64; ++i) {
            float a = A[i];
            float4 w4 = *(const float4*)(wbase + i * INDIM);
            a0 += a * w4.x; a1 += a * w4.y; a2 += a * w4.z; a3 += a * w4.w;
            accb += a * bbase[i];
        }
        float* red  = smem;              // [4][8][33]
        float* redb = smem + 4 * 8 * 33; // [4][8]
        int rb = (row * 8 + kc) * 33 + j4 * 4;
        red[rb + 0] = a0; red[rb + 1] = a1; red[rb + 2] = a2; red[rb + 3] = a3;
        if (j4 == 0) redb[row * 8 + kc] = accb;
        __syncthreads();
        if (tid < 128) {
            int r = tid >> 5, j = tid & 31;
            float s = 0.f;
            #pragma unroll
            for (int k2 = 0; k2 < 8; ++k2) s += red[(r * 8 + k2) * 33 + j];
            int e = e0 + r;
            if (mat == 0) wq2[e * INDIM + j] = s;
            else if (mat == 1) wk2b[e * INDIM + j] = f2bf(s);
            else wv2[e * INDIM + j] = s;
        } else if (tid < 132) {
            int r = tid - 128;
            float s = 0.f;
            #pragma unroll
            for (int k2 = 0; k2 < 8; ++k2) s += redb[r * 8 + k2];
            int e = e0 + r;
            if (mat == 0) bq2[e] = bq[e] + s;
            else if (mat == 1) bk2[e] = bk[e] + s;
            else wvb[e] = s + bv[e];
        }
    } else if (bid < 512) {
        int e0 = (bid - 384) * 4;
        int row = tid >> 6, kc = (tid >> 3) & 7, j4 = tid & 7;
        const float* A = wff1 + (long)(e0 + row) * DIM + kc * 64;
        const float* wbase = w_in + (kc * 64) * INDIM + j4 * 4;
        int dbase = kc * 64;
        float a0 = 0.f, a1 = 0.f, a2 = 0.f, a3 = 0.f;
        float accc = 0.f, accg = 0.f, accb1 = 0.f;
        #pragma unroll 4
        for (int i = 0; i < 64; ++i) {
            int d = dbase + i;
            float a = A[i], g = g1[d], ag = a * g;
            float4 w4 = *(const float4*)(wbase + i * INDIM);
            a0 += ag * w4.x; a1 += ag * w4.y; a2 += ag * w4.z; a3 += ag * w4.w;
            accc += ag * (b_in[d] + bo[d]);
            accg += ag;
            accb1 += a * b1[d];
        }
        float* red  = smem;                    // [4][8][33]
        float* red2 = smem + 4 * 8 * 33;       // [4][8][3]
        int rb = (row * 8 + kc) * 33 + j4 * 4;
        red[rb + 0] = a0; red[rb + 1] = a1; red[rb + 2] = a2; red[rb + 3] = a3;
        if (j4 == 0) {
            int b2 = (row * 8 + kc) * 3;
            red2[b2 + 0] = accc; red2[b2 + 1] = accg; red2[b2 + 2] = accb1;
        }
        __syncthreads();
        if (tid < 128) {
            int r = tid >> 5, j = tid & 31;
            float s = 0.f;
            #pragma unroll
            for (int k2 = 0; k2 < 8; ++k2) s += red[(r * 8 + k2) * 33 + j];
            wf1x[(e0 + r) * INDIM + j] = s;
        } else if (tid < 132) {
            int r = tid - 128;
            float sc = 0.f, sg = 0.f, sb = 0.f;
            #pragma unroll
            for (int k2 = 0; k2 < 8; ++k2) {
                int b2 = (r * 8 + k2) * 3;
                sc += red2[b2 + 0]; sg += red2[b2 + 1]; sb += red2[b2 + 2];
            }
            int e = e0 + r;
            wf1c[e] = sc; wg1[e] = sg; wb1[e] = sb;
            bb[e] = b_in[e] + bo[e];
        }
    } else {
        // transpose+cvt: MT[k][d] = bf16(M[d][k] * (m==1 ? g1[k] : 1)); 64x64 tiles
        int t = bid - 512;             // 0..191
        int m = t >> 6;                // 0 wo, 1 wff1*g1, 2 wff2
        int tt = t & 63;
        int r = tt >> 3, c = tt & 7;   // d-tile, k-tile
        const float* M = (m == 0) ? wo : (m == 1 ? wff1 : wff2);
        u16* MT = (m == 0) ? woT : (m == 1 ? wff1g1T : wff2T);
        float* tile = smem;            // [64][65]
        int rr = tid >> 2, cc = (tid & 3) * 16;
        const float* src = M + (long)(r * 64 + rr) * DIM + c * 64 + cc;
        #pragma unroll
        for (int i = 0; i < 4; ++i) {
            float4 v = *(const float4*)(src + i * 4);
            tile[rr * 65 + cc + i * 4 + 0] = v.x;
            tile[rr * 65 + cc + i * 4 + 1] = v.y;
            tile[rr * 65 + cc + i * 4 + 2] = v.z;
            tile[rr * 65 + cc + i * 4 + 3] = v.w;
        }
        __syncthreads();
        int orr = tid >> 2, occ = (tid & 3) * 16;   // k-local, d-chunk
        float gk = (m == 1) ? g1[c * 64 + orr] : 1.f;
        u16 ob[16];
        #pragma unroll
        for (int i = 0; i < 16; ++i) ob[i] = f2bf(tile[(occ + i) * 65 + orr] * gk);
        u16* dst = MT + (long)(c * 64 + orr) * DIM + r * 64 + occ;
        *(ushort8*)dst = *(ushort8*)ob;
        *(ushort8*)(dst + 8) = *(ushort8*)(ob + 8);
    }
}

// ===================== k_w: 512 token tiles (r13-verified, WBM=128) =====================
__global__ __launch_bounds__(256) void k_w(
    const float* __restrict__ x,
    const float* __restrict__ wq2, const float* __restrict__ bq2,
    const u16* __restrict__ wk2b, const float* __restrict__ bk2,
    float* __restrict__ xup, float* __restrict__ zdp) {
    __shared__ u16 sB[DIM * 40];       // 40960 B
    __shared__ float s_q0[DIM];        // 2048
    __shared__ float sw[WBM];          // 512
    __shared__ float sxu8[8][32];      // 1024
    __shared__ float szz[8];           // 32
    __shared__ float sx0[INDIM];       // 128
    int tid = threadIdx.x;
    int tt = blockIdx.x;
    int lane = tid & 63, wid = tid >> 6;
    long tbase = (long)tt * WBM;
    int batch = (int)(tbase >> 12);

    #pragma unroll
    for (int pp = 0; pp < 8; ++pp) {
        int f = (pp * 256 + tid) * 8;
        int row = f >> 5, colc = f & 31;
        ushort8 v = *(const ushort8*)(wk2b + f);
        *(ushort8*)(sB + row * 40 + colc) = v;
    }
    if (tid < INDIM) sx0[tid] = x[(long)batch * SEQ * INDIM + tid];
    __syncthreads();
    #pragma unroll
    for (int rep = 0; rep < 2; ++rep) {
        int e = tid + rep * 256;
        float a = bq2[e] + dot32(wq2 + e * INDIM, sx0);
        s_q0[e] = (a > 0.f) ? (a + 1.f) : __expf(a);
    }

    int col = lane & 15;
    int koff = (lane >> 4) * 8;
    bf16x8 fa[2];
    #pragma unroll
    for (int mi = 0; mi < 2; ++mi) {
        const float* xr = x + (tbase + wid * 32 + mi * 16 + col) * INDIM + koff;
        float4 a0 = *(const float4*)(xr);
        float4 a1 = *(const float4*)(xr + 4);
        u16 tmp[8] = { f2bf(a0.x), f2bf(a0.y), f2bf(a0.z), f2bf(a0.w),
                       f2bf(a1.x), f2bf(a1.y), f2bf(a1.z), f2bf(a1.w) };
        fa[mi] = *(bf16x8*)tmp;
    }
    __syncthreads();

    float q0v[32], bkv[32];
    #pragma unroll
    for (int ni = 0; ni < 32; ++ni) {
        q0v[ni] = s_q0[ni * 16 + col];
        bkv[ni] = bk2[ni * 16 + col];
    }

    f32x4 zero = {0.f, 0.f, 0.f, 0.f};
    float wpart[2][4] = {};
    #pragma unroll
    for (int nc = 0; nc < 4; ++nc) {
        bf16x8 fb[8];
        #pragma unroll
        for (int nj = 0; nj < 8; ++nj) {
            int row = (nc * 8 + nj) * 16 + col;
            fb[nj] = *(const bf16x8*)(sB + row * 40 + koff);
        }
        #pragma unroll
        for (int mi = 0; mi < 2; ++mi) {
            #pragma unroll
            for (int nj = 0; nj < 8; ++nj) {
                f32x4 acc = __builtin_amdgcn_mfma_f32_16x16x32_bf16(fa[mi], fb[nj], zero, 0, 0, 0);
                int ni = nc * 8 + nj;
                #pragma unroll
                for (int r = 0; r < 4; ++r) {
                    float v = acc[r] + bkv[ni];
                    v = (v > 0.f) ? (v + 1.f) : __expf(v);
                    wpart[mi][r] += v * q0v[ni];
                }
            }
        }
    }
    #pragma unroll
    for (int mi = 0; mi < 2; ++mi) {
        #pragma unroll
        for (int r = 0; r < 4; ++r) {
            float s = wpart[mi][r];
            s += __shfl_xor(s, 1, 64); s += __shfl_xor(s, 2, 64);
            s += __shfl_xor(s, 4, 64); s += __shfl_xor(s, 8, 64);
            if (col == 0) sw[wid * 32 + mi * 16 + (lane >> 4) * 4 + r] = s;
        }
    }
    __syncthreads();
    {
        int j = tid & 31, g = tid >> 5;
        float a = 0.f, z = 0.f;
        for (int tl = g; tl < WBM; tl += 8) {
            float wv_ = sw[tl];
            a += wv_ * x[(tbase + tl) * INDIM + j];
            if (j == 0) z += wv_;
        }
        sxu8[g][j] = a;
        if (j == 0) szz[g] = z;
    }
    __syncthreads();
    if (tid < 32) {
        float a = 0.f;
        #pragma unroll
        for (int g = 0; g < 8; ++g) a += sxu8[g][tid];
        xup[tt * INDIM + tid] = a;
    } else if (tid == 32) {
        float z = 0.f;
        #pragma unroll
        for (int g = 0; g < 8; ++g) z += szz[g];
        zdp[tt] = z;
    }
}

// ===================== k_final: 1024 threads, 16-way k-split GEMVs =====================
__device__ __forceinline__ void reduce2_1024(float a, float b, int tid, float* l32,
                                             float& oa, float& ob) {
    #pragma unroll
    for (int off = 1; off < 64; off <<= 1) {
        a += __shfl_xor(a, off, 64);
        b += __shfl_xor(b, off, 64);
    }
    int w = tid >> 6;   // 0..15
    if ((tid & 63) == 0) { l32[w] = a; l32[16 + w] = b; }
    __syncthreads();
    float ra = 0.f, rb = 0.f;
    #pragma unroll
    for (int i = 0; i < 16; ++i) { ra += l32[i]; rb += l32[16 + i]; }
    oa = ra; ob = rb;
    __syncthreads();
}

// coalesced GEMV: out_d = sum_k MT[k][d]*vec[k]; 16-way k-split, 1024 threads.
// All threads participate; result valid for tid<512 (d=tid).
__device__ __forceinline__ float gemv1024(const u16* __restrict__ MT,
                                          const float* __restrict__ vec,
                                          float* __restrict__ spart,
                                          int tid) {
    int kc = tid >> 6, dg = tid & 63;    // kc 0..15
    float ps[8] = {};
    const u16* base = MT + (long)(kc * 32) * DIM + dg * 8;
    #pragma unroll 8
    for (int k8 = 0; k8 < 32; ++k8) {
        ushort8 w8 = *(const ushort8*)(base + (long)k8 * DIM);
        float fk = vec[kc * 32 + k8];
        #pragma unroll
        for (int j = 0; j < 8; ++j) ps[j] += bf2f(w8[j]) * fk;
    }
    #pragma unroll
    for (int j = 0; j < 8; ++j) spart[kc * DIM + dg * 8 + j] = ps[j];
    __syncthreads();
    float acc = 0.f;
    if (tid < DIM) {
        #pragma unroll
        for (int i = 0; i < 16; ++i) acc += spart[i * DIM + tid];
    }
    return acc;
}

__global__ __launch_bounds__(1024) void k_final(
    const float* __restrict__ x, const float* __restrict__ w_in,
    const float* __restrict__ wv2, const float* __restrict__ wvb,
    const float* __restrict__ bb,
    const float* __restrict__ wf1x, const float* __restrict__ wf1c,
    const float* __restrict__ wg1, const float* __restrict__ wb1,
    const float* __restrict__ g1, const float* __restrict__ b1,
    const float* __restrict__ bff1, const float* __restrict__ bff2,
    const u16* __restrict__ woT, const u16* __restrict__ wff1g1T,
    const u16* __restrict__ wff2T,
    const float* __restrict__ g2, const float* __restrict__ b2,
    const float* __restrict__ gf, const float* __restrict__ bfv,
    const float* __restrict__ wfc, const float* __restrict__ bfc,
    const float* __restrict__ xup, const float* __restrict__ zdp,
    float* __restrict__ out) {
    __shared__ float sx0[INDIM], sxu[INDIM];
    __shared__ float sv[DIM];
    __shared__ float sf[DIM];
    __shared__ float spart[16 * DIM];   // 32 KiB
    __shared__ float l32[32];
    __shared__ float szd;
    int n = blockIdx.x, tid = threadIdx.x;
    bool lo = tid < DIM;
    int d = tid & (DIM - 1);
    if (tid < INDIM) {
        float a = 0.f;
        #pragma unroll 8
        for (int slot = 0; slot < 32; ++slot)
            a += xup[(n * 32 + slot) * INDIM + tid];
        sxu[tid] = a;
        sx0[tid] = x[(long)n * SEQ * INDIM + tid];
    } else if (tid == 32) {
        float z = 0.f;
        #pragma unroll 8
        for (int slot = 0; slot < 32; ++slot) z += zdp[n * 32 + slot];
        szd = z;
    }
    __syncthreads();
    float zd = szd;
    float Z = 1.f / (zd + 1e-6f);
    float zz = zd * Z;

    // u2 = wv2 @ xu ; GEMV-A input v = Z*u2 + zz*wvb
    if (lo) {
        float u2d = dot32(wv2 + (long)d * INDIM, sxu);
        sv[d] = Z * u2d + zz * wvb[d];
    }
    __syncthreads();

    // o = wo @ v  (coalesced woT)
    float o_d = gemv1024(woT, sv, spart, tid);

    // r = bb + w_in@x0 + o ; LN1  (reduce's syncs fence spart reuse)
    float rd = 0.f;
    if (lo) {
        rd = bb[d] + dot32(w_in + (long)d * INDIM, sx0) + o_d;
        sv[d] = o_d;   // GEMV-B input (g1 folded into wff1g1T)
    }
    float sum, sumsq;
    reduce2_1024(lo ? rd : 0.f, lo ? rd * rd : 0.f, tid, l32, sum, sumsq);
    float mu1 = sum * (1.f / DIM);
    float s1 = rsqrtf(sumsq * (1.f / DIM) - mu1 * mu1 + 1e-5f);
    float r1 = lo ? ((rd - mu1) * s1 * g1[d] + b1[d]) : 0.f;

    // G = wf1x@x0 + (wff1*g1)@o + wf1c ; fpre ; f = relu
    float W_d = gemv1024(wff1g1T, sv, spart, tid);
    float fp = 0.f;
    if (lo) {
        float G = dot32(wf1x + (long)d * INDIM, sx0) + W_d + wf1c[d];
        fp = s1 * (G - mu1 * wg1[d]) + wb1[d] + bff1[d];
    }
    __syncthreads();            // fence spart reads before GEMV-C writes
    if (lo) sf[d] = fmaxf(fp, 0.f);
    __syncthreads();

    // y = r1 + wff2@f + bff2
    float yacc = gemv1024(wff2T, sf, spart, tid);
    float y = lo ? (r1 + bff2[d] + yacc) : 0.f;

    reduce2_1024(lo ? y : 0.f, lo ? y * y : 0.f, tid, l32, sum, sumsq);
    float mu2 = sum * (1.f / DIM);
    float inv2 = rsqrtf(sumsq * (1.f / DIM) - mu2 * mu2 + 1e-5f);
    float h2 = lo ? ((y - mu2) * inv2 * g2[d] + b2[d]) : 0.f;

    reduce2_1024(lo ? h2 : 0.f, lo ? h2 * h2 : 0.f, tid, l32, sum, sumsq);
    float mu3 = sum * (1.f / DIM);
    float inv3 = rsqrtf(sumsq * (1.f / DIM) - mu3 * mu3 + 1e-5f);
    float h3 = lo ? ((h2 - mu3) * inv3 * gf[d] + bfv[d]) : 0.f;

    float pfc = lo ? (wfc[d] * h3) : 0.f;
    float dummy;
    reduce2_1024(pfc, 0.f, tid, l32, sum, dummy);
    if (tid == 0) out[n] = sum + bfc[0];
}

extern "C" void kernel_launch(void* const* d_in, const int* in_sizes, int n_in,
                              void* d_out, int out_size, void* d_ws, size_t ws_size,
                              hipStream_t stream) {
    const float* x    = (const float*)d_in[0];
    const float* w_in = (const float*)d_in[1];
    const float* b_in = (const float*)d_in[2];
    const float* wq   = (const float*)d_in[3];
    const float* bq   = (const float*)d_in[4];
    const float* wk   = (const float*)d_in[5];
    const float* bk   = (const float*)d_in[6];
    const float* wv   = (const float*)d_in[7];
    const float* bv   = (const float*)d_in[8];
    const float* wo   = (const float*)d_in[9];
    const float* bo   = (const float*)d_in[10];
    const float* g1   = (const float*)d_in[11];
    const float* b1   = (const float*)d_in[12];
    const float* wff1 = (const float*)d_in[13];
    const float* bff1 = (const float*)d_in[14];
    const float* wff2 = (const float*)d_in[15];
    const float* bff2 = (const float*)d_in[16];
    const float* g2   = (const float*)d_in[17];
    const float* b2   = (const float*)d_in[18];
    const float* gf   = (const float*)d_in[19];
    const float* bf   = (const float*)d_in[20];
    const float* wfc  = (const float*)d_in[21];
    const float* bfc  = (const float*)d_in[22];

    char* ws = (char*)d_ws;
    float* wq2     = (float*)(ws + 0);         // 64 KiB
    float* bq2     = (float*)(ws + 65536);     // 2 KiB
    u16*   wk2b    = (u16*)  (ws + 67584);     // 32 KiB
    float* bk2     = (float*)(ws + 100352);    // 2 KiB
    float* wv2     = (float*)(ws + 102400);    // 64 KiB
    float* wvb     = (float*)(ws + 167936);    // 2 KiB
    float* bb      = (float*)(ws + 169984);    // 2 KiB
    float* wf1x    = (float*)(ws + 172032);    // 64 KiB
    float* wf1c    = (float*)(ws + 237568);    // 2 KiB
    float* wg1     = (float*)(ws + 239616);    // 2 KiB
    float* wb1     = (float*)(ws + 241664);    // 2 KiB
    u16*   woT     = (u16*)  (ws + 243712);    // 512 KiB
    u16*   wff1g1T = (u16*)  (ws + 767872);    // 512 KiB
    u16*   wff2T   = (u16*)  (ws + 1292160);   // 512 KiB
    float* xup     = (float*)(ws + 1816448);   // 64 KiB  [512][32]
    float* zdp     = (float*)(ws + 1881984);   // 2 KiB   [512]

    k_p1<<<704, 256, 0, stream>>>(x, w_in, b_in, wq, bq, wk, bk, wv, bv, wo, bo,
                                  g1, b1, wff1, wff2,
                                  wq2, bq2, wk2b, bk2, wv2, wvb,
                                  wf1x, wf1c, wg1, wb1, bb,
                                  woT, wff1g1T, wff2T);
    k_w<<<NTILE, 256, 0, stream>>>(x, wq2, bq2, wk2b, bk2, xup, zdp);
    k_final<<<NB, 1024, 0, stream>>>(x, w_in, wv2, wvb, bb, wf1x, wf1c, wg1, wb1,
                                     g1, b1, bff1, bff2, woT, wff1g1T, wff2T,
                                     g2, b2, gf, bf, wfc, bfc, xup, zdp,
                                     (float*)d_out);
}

// Round 16
// 64.736 us; speedup vs baseline: 1.1498x; 1.0339x over previous
//
#include <hip/hip_runtime.h>
#include <hip/hip_bf16.h>

typedef unsigned short u16;
typedef __attribute__((ext_vector_type(8))) unsigned short ushort8;
typedef __attribute__((ext_vector_type(8))) __bf16 bf16x8;
typedef __attribute__((ext_vector_type(4))) float f32x4;

// N=16, L=4096, IN_DIM=32, D=E=512
#define NB 16
#define SEQ 4096
#define DIM 512
#define INDIM 32
#define NTOK (NB * SEQ)    // 65536
#define WBM 128            // tokens per k_w tile
#define NTILE (NTOK / WBM) // 512

static __device__ __forceinline__ u16 f2bf(float f) {
    union { float f; unsigned u; } x; x.f = f;
    unsigned r = (x.u + 0x7FFFu + ((x.u >> 16) & 1u)) >> 16;
    return (u16)r;
}
static __device__ __forceinline__ float bf2f(u16 b) {
    union { unsigned u; float f; } x; x.u = ((unsigned)b) << 16;
    return x.f;
}

__device__ __forceinline__ float dot32(const float* __restrict__ w, const float* v) {
    const float4* a = (const float4*)w;
    float acc = 0.f;
    #pragma unroll
    for (int i = 0; i < 8; ++i) {
        float4 p = a[i];
        acc += p.x * v[4*i] + p.y * v[4*i+1] + p.z * v[4*i+2] + p.w * v[4*i+3];
    }
    return acc;
}

// ===================== k_p1: input-only precomputes (r13-verified) =====================
// grid 704:
//   [0,384):   mats wq/wk/wv -> wq2/bq2, wk2b/bk2, wv2/wvb. 4 rows/block, float4 w_in loads.
//   [384,512): wff1 rows -> wf1x, wf1c, wg1, wb1, bb. 4 rows/block.
//   [512,704): bf16 transposes MT[k][d]: m=0 wo, m=1 wff1*g1, m=2 wff2 (64 tiles each)
__global__ __launch_bounds__(256) void k_p1(
    const float* __restrict__ x,
    const float* __restrict__ w_in, const float* __restrict__ b_in,
    const float* __restrict__ wq, const float* __restrict__ bq,
    const float* __restrict__ wk, const float* __restrict__ bk,
    const float* __restrict__ wv, const float* __restrict__ bv,
    const float* __restrict__ wo, const float* __restrict__ bo,
    const float* __restrict__ g1, const float* __restrict__ b1,
    const float* __restrict__ wff1, const float* __restrict__ wff2,
    float* __restrict__ wq2, float* __restrict__ bq2,
    u16* __restrict__ wk2b, float* __restrict__ bk2,
    float* __restrict__ wv2, float* __restrict__ wvb,
    float* __restrict__ wf1x, float* __restrict__ wf1c,
    float* __restrict__ wg1, float* __restrict__ wb1, float* __restrict__ bb,
    u16* __restrict__ woT, u16* __restrict__ wff1g1T, u16* __restrict__ wff2T) {
    __shared__ float smem[64 * 65];   // 16.6 KiB, reused per segment
    int bid = blockIdx.x, tid = threadIdx.x;

    if (bid < 384) {
        int mat = bid >> 7, e0 = (bid & 127) * 4;
        int row = tid >> 6, kc = (tid >> 3) & 7, j4 = tid & 7;
        const float* A = (mat == 0 ? wq : (mat == 1 ? wk : wv))
                       + (long)(e0 + row) * DIM + kc * 64;
        const float* wbase = w_in + (kc * 64) * INDIM + j4 * 4;
        const float* bbase = b_in + kc * 64;
        float a0 = 0.f, a1 = 0.f, a2 = 0.f, a3 = 0.f, accb = 0.f;
        #pragma unroll 8
        for (int i = 0; i < 64; ++i) {
            float a = A[i];
            float4 w4 = *(const float4*)(wbase + i * INDIM);
            a0 += a * w4.x; a1 += a * w4.y; a2 += a * w4.z; a3 += a * w4.w;
            accb += a * bbase[i];
        }
        float* red  = smem;              // [4][8][33]
        float* redb = smem + 4 * 8 * 33; // [4][8]
        int rb = (row * 8 + kc) * 33 + j4 * 4;
        red[rb + 0] = a0; red[rb + 1] = a1; red[rb + 2] = a2; red[rb + 3] = a3;
        if (j4 == 0) redb[row * 8 + kc] = accb;
        __syncthreads();
        if (tid < 128) {
            int r = tid >> 5, j = tid & 31;
            float s = 0.f;
            #pragma unroll
            for (int k2 = 0; k2 < 8; ++k2) s += red[(r * 8 + k2) * 33 + j];
            int e = e0 + r;
            if (mat == 0) wq2[e * INDIM + j] = s;
            else if (mat == 1) wk2b[e * INDIM + j] = f2bf(s);
            else wv2[e * INDIM + j] = s;
        } else if (tid < 132) {
            int r = tid - 128;
            float s = 0.f;
            #pragma unroll
            for (int k2 = 0; k2 < 8; ++k2) s += redb[r * 8 + k2];
            int e = e0 + r;
            if (mat == 0) bq2[e] = bq[e] + s;
            else if (mat == 1) bk2[e] = bk[e] + s;
            else wvb[e] = s + bv[e];
        }
    } else if (bid < 512) {
        int e0 = (bid - 384) * 4;
        int row = tid >> 6, kc = (tid >> 3) & 7, j4 = tid & 7;
        const float* A = wff1 + (long)(e0 + row) * DIM + kc * 64;
        const float* wbase = w_in + (kc * 64) * INDIM + j4 * 4;
        int dbase = kc * 64;
        float a0 = 0.f, a1 = 0.f, a2 = 0.f, a3 = 0.f;
        float accc = 0.f, accg = 0.f, accb1 = 0.f;
        #pragma unroll 4
        for (int i = 0; i < 64; ++i) {
            int d = dbase + i;
            float a = A[i], g = g1[d], ag = a * g;
            float4 w4 = *(const float4*)(wbase + i * INDIM);
            a0 += ag * w4.x; a1 += ag * w4.y; a2 += ag * w4.z; a3 += ag * w4.w;
            accc += ag * (b_in[d] + bo[d]);
            accg += ag;
            accb1 += a * b1[d];
        }
        float* red  = smem;                    // [4][8][33]
        float* red2 = smem + 4 * 8 * 33;       // [4][8][3]
        int rb = (row * 8 + kc) * 33 + j4 * 4;
        red[rb + 0] = a0; red[rb + 1] = a1; red[rb + 2] = a2; red[rb + 3] = a3;
        if (j4 == 0) {
            int b2 = (row * 8 + kc) * 3;
            red2[b2 + 0] = accc; red2[b2 + 1] = accg; red2[b2 + 2] = accb1;
        }
        __syncthreads();
        if (tid < 128) {
            int r = tid >> 5, j = tid & 31;
            float s = 0.f;
            #pragma unroll
            for (int k2 = 0; k2 < 8; ++k2) s += red[(r * 8 + k2) * 33 + j];
            wf1x[(e0 + r) * INDIM + j] = s;
        } else if (tid < 132) {
            int r = tid - 128;
            float sc = 0.f, sg = 0.f, sb = 0.f;
            #pragma unroll
            for (int k2 = 0; k2 < 8; ++k2) {
                int b2 = (r * 8 + k2) * 3;
                sc += red2[b2 + 0]; sg += red2[b2 + 1]; sb += red2[b2 + 2];
            }
            int e = e0 + r;
            wf1c[e] = sc; wg1[e] = sg; wb1[e] = sb;
            bb[e] = b_in[e] + bo[e];
        }
    } else {
        // transpose+cvt: MT[k][d] = bf16(M[d][k] * (m==1 ? g1[k] : 1)); 64x64 tiles
        int t = bid - 512;             // 0..191
        int m = t >> 6;                // 0 wo, 1 wff1*g1, 2 wff2
        int tt = t & 63;
        int r = tt >> 3, c = tt & 7;   // d-tile, k-tile
        const float* M = (m == 0) ? wo : (m == 1 ? wff1 : wff2);
        u16* MT = (m == 0) ? woT : (m == 1 ? wff1g1T : wff2T);
        float* tile = smem;            // [64][65]
        int rr = tid >> 2, cc = (tid & 3) * 16;
        const float* src = M + (long)(r * 64 + rr) * DIM + c * 64 + cc;
        #pragma unroll
        for (int i = 0; i < 4; ++i) {
            float4 v = *(const float4*)(src + i * 4);
            tile[rr * 65 + cc + i * 4 + 0] = v.x;
            tile[rr * 65 + cc + i * 4 + 1] = v.y;
            tile[rr * 65 + cc + i * 4 + 2] = v.z;
            tile[rr * 65 + cc + i * 4 + 3] = v.w;
        }
        __syncthreads();
        int orr = tid >> 2, occ = (tid & 3) * 16;   // k-local, d-chunk
        float gk = (m == 1) ? g1[c * 64 + orr] : 1.f;
        u16 ob[16];
        #pragma unroll
        for (int i = 0; i < 16; ++i) ob[i] = f2bf(tile[(occ + i) * 65 + orr] * gk);
        u16* dst = MT + (long)(c * 64 + orr) * DIM + r * 64 + occ;
        *(ushort8*)dst = *(ushort8*)ob;
        *(ushort8*)(dst + 8) = *(ushort8*)(ob + 8);
    }
}

// ===================== k_w: 512 token tiles (q0 computed in-block from wq2) =====================
__global__ __launch_bounds__(256) void k_w(
    const float* __restrict__ x,
    const float* __restrict__ wq2, const float* __restrict__ bq2,
    const u16* __restrict__ wk2b, const float* __restrict__ bk2,
    float* __restrict__ xup, float* __restrict__ zdp) {
    __shared__ u16 sB[DIM * 40];       // 40960 B
    __shared__ float s_q0[DIM];        // 2048
    __shared__ float sw[WBM];          // 512
    __shared__ float sxu8[8][32];      // 1024
    __shared__ float szz[8];           // 32
    __shared__ float sx0[INDIM];       // 128
    int tid = threadIdx.x;
    int tt = blockIdx.x;
    int lane = tid & 63, wid = tid >> 6;
    long tbase = (long)tt * WBM;
    int batch = (int)(tbase >> 12);

    #pragma unroll
    for (int pp = 0; pp < 8; ++pp) {
        int f = (pp * 256 + tid) * 8;
        int row = f >> 5, colc = f & 31;
        ushort8 v = *(const ushort8*)(wk2b + f);
        *(ushort8*)(sB + row * 40 + colc) = v;
    }
    if (tid < INDIM) sx0[tid] = x[(long)batch * SEQ * INDIM + tid];
    __syncthreads();
    #pragma unroll
    for (int rep = 0; rep < 2; ++rep) {
        int e = tid + rep * 256;
        float a = bq2[e] + dot32(wq2 + e * INDIM, sx0);
        s_q0[e] = (a > 0.f) ? (a + 1.f) : __expf(a);
    }

    int col = lane & 15;
    int koff = (lane >> 4) * 8;
    bf16x8 fa[2];
    #pragma unroll
    for (int mi = 0; mi < 2; ++mi) {
        const float* xr = x + (tbase + wid * 32 + mi * 16 + col) * INDIM + koff;
        float4 a0 = *(const float4*)(xr);
        float4 a1 = *(const float4*)(xr + 4);
        u16 tmp[8] = { f2bf(a0.x), f2bf(a0.y), f2bf(a0.z), f2bf(a0.w),
                       f2bf(a1.x), f2bf(a1.y), f2bf(a1.z), f2bf(a1.w) };
        fa[mi] = *(bf16x8*)tmp;
    }
    __syncthreads();

    float q0v[32], bkv[32];
    #pragma unroll
    for (int ni = 0; ni < 32; ++ni) {
        q0v[ni] = s_q0[ni * 16 + col];
        bkv[ni] = bk2[ni * 16 + col];
    }

    f32x4 zero = {0.f, 0.f, 0.f, 0.f};
    float wpart[2][4] = {};
    #pragma unroll
    for (int nc = 0; nc < 4; ++nc) {
        bf16x8 fb[8];
        #pragma unroll
        for (int nj = 0; nj < 8; ++nj) {
            int row = (nc * 8 + nj) * 16 + col;
            fb[nj] = *(const bf16x8*)(sB + row * 40 + koff);
        }
        #pragma unroll
        for (int mi = 0; mi < 2; ++mi) {
            #pragma unroll
            for (int nj = 0; nj < 8; ++nj) {
                f32x4 acc = __builtin_amdgcn_mfma_f32_16x16x32_bf16(fa[mi], fb[nj], zero, 0, 0, 0);
                int ni = nc * 8 + nj;
                #pragma unroll
                for (int r = 0; r < 4; ++r) {
                    float v = acc[r] + bkv[ni];
                    v = (v > 0.f) ? (v + 1.f) : __expf(v);
                    wpart[mi][r] += v * q0v[ni];
                }
            }
        }
    }
    #pragma unroll
    for (int mi = 0; mi < 2; ++mi) {
        #pragma unroll
        for (int r = 0; r < 4; ++r) {
            float s = wpart[mi][r];
            s += __shfl_xor(s, 1, 64); s += __shfl_xor(s, 2, 64);
            s += __shfl_xor(s, 4, 64); s += __shfl_xor(s, 8, 64);
            if (col == 0) sw[wid * 32 + mi * 16 + (lane >> 4) * 4 + r] = s;
        }
    }
    __syncthreads();
    {
        int j = tid & 31, g = tid >> 5;
        float a = 0.f, z = 0.f;
        for (int tl = g; tl < WBM; tl += 8) {
            float wv_ = sw[tl];
            a += wv_ * x[(tbase + tl) * INDIM + j];
            if (j == 0) z += wv_;
        }
        sxu8[g][j] = a;
        if (j == 0) szz[g] = z;
    }
    __syncthreads();
    if (tid < 32) {
        float a = 0.f;
        #pragma unroll
        for (int g = 0; g < 8; ++g) a += sxu8[g][tid];
        xup[tt * INDIM + tid] = a;
    } else if (tid == 32) {
        float z = 0.f;
        #pragma unroll
        for (int g = 0; g < 8; ++g) z += szz[g];
        zdp[tt] = z;
    }
}

// ===================== k_final: 3 coalesced GEMVs + LNs (r13-verified) =====================
__device__ __forceinline__ void reduce2_512(float a, float b, int tid, float* l16,
                                            float& oa, float& ob) {
    #pragma unroll
    for (int off = 1; off < 64; off <<= 1) {
        a += __shfl_xor(a, off, 64);
        b += __shfl_xor(b, off, 64);
    }
    int w = tid >> 6;
    if ((tid & 63) == 0) { l16[w] = a; l16[8 + w] = b; }
    __syncthreads();
    float ra = 0.f, rb = 0.f;
    #pragma unroll
    for (int i = 0; i < 8; ++i) { ra += l16[i]; rb += l16[8 + i]; }
    oa = ra; ob = rb;
    __syncthreads();
}

// coalesced GEMV: out_d = sum_k MT[k][d] * vec[k]; 8-way k-split, 512 threads.
__device__ __forceinline__ float gemv512(const u16* __restrict__ MT,
                                         const float* __restrict__ vec,
                                         float* __restrict__ spart,
                                         int tid, int d) {
    int kc = tid >> 6, dg = tid & 63;
    float ps[8] = {};
    const u16* base = MT + (long)(kc * 64) * DIM + dg * 8;
    #pragma unroll 8
    for (int k8 = 0; k8 < 64; ++k8) {
        ushort8 w8 = *(const ushort8*)(base + (long)k8 * DIM);
        float fk = vec[kc * 64 + k8];
        #pragma unroll
        for (int j = 0; j < 8; ++j) ps[j] += bf2f(w8[j]) * fk;
    }
    #pragma unroll
    for (int j = 0; j < 8; ++j) spart[kc * DIM + dg * 8 + j] = ps[j];
    __syncthreads();
    float acc = 0.f;
    #pragma unroll
    for (int i = 0; i < 8; ++i) acc += spart[i * DIM + d];
    return acc;
}

__global__ __launch_bounds__(512) void k_final(
    const float* __restrict__ x, const float* __restrict__ w_in,
    const float* __restrict__ wv2, const float* __restrict__ wvb,
    const float* __restrict__ bb,
    const float* __restrict__ wf1x, const float* __restrict__ wf1c,
    const float* __restrict__ wg1, const float* __restrict__ wb1,
    const float* __restrict__ g1, const float* __restrict__ b1,
    const float* __restrict__ bff1, const float* __restrict__ bff2,
    const u16* __restrict__ woT, const u16* __restrict__ wff1g1T,
    const u16* __restrict__ wff2T,
    const float* __restrict__ g2, const float* __restrict__ b2,
    const float* __restrict__ gf, const float* __restrict__ bfv,
    const float* __restrict__ wfc, const float* __restrict__ bfc,
    const float* __restrict__ xup, const float* __restrict__ zdp,
    float* __restrict__ out) {
    __shared__ float sx0[INDIM], sxu[INDIM];
    __shared__ float sv[DIM];
    __shared__ float sf[DIM];
    __shared__ float spart[8 * DIM];   // 16 KiB
    __shared__ float l16[16];
    __shared__ float szd;
    int n = blockIdx.x, tid = threadIdx.x, d = tid;
    if (tid < INDIM) {
        float a = 0.f;
        #pragma unroll 8
        for (int slot = 0; slot < 32; ++slot)
            a += xup[(n * 32 + slot) * INDIM + tid];
        sxu[tid] = a;
        sx0[tid] = x[(long)n * SEQ * INDIM + tid];
    } else if (tid == 32) {
        float z = 0.f;
        #pragma unroll 8
        for (int slot = 0; slot < 32; ++slot) z += zdp[n * 32 + slot];
        szd = z;
    }
    __syncthreads();
    float zd = szd;
    float Z = 1.f / (zd + 1e-6f);
    float zz = zd * Z;

    // u2 = wv2 @ xu ; GEMV-A input v = Z*u2 + zz*wvb
    float u2d = dot32(wv2 + d * INDIM, sxu);
    sv[d] = Z * u2d + zz * wvb[d];
    __syncthreads();

    // o = wo @ v  (coalesced woT)
    float o_d = gemv512(woT, sv, spart, tid, d);

    // r = bb + w_in@x0 + o ; LN1  (reduce's syncs also fence spart reuse)
    float rd = bb[d] + dot32(w_in + d * INDIM, sx0) + o_d;
    sv[d] = o_d;   // GEMV-B input (g1 folded into wff1g1T)
    float sum, sumsq;
    reduce2_512(rd, rd * rd, tid, l16, sum, sumsq);
    float mu1 = sum * (1.f / DIM);
    float s1 = rsqrtf(sumsq * (1.f / DIM) - mu1 * mu1 + 1e-5f);
    float r1 = (rd - mu1) * s1 * g1[d] + b1[d];

    // G = wf1x@x0 + (wff1*g1)@o + wf1c ; fpre ; f = relu
    float W_d = gemv512(wff1g1T, sv, spart, tid, d);
    float G = dot32(wf1x + d * INDIM, sx0) + W_d + wf1c[d];
    float fp = s1 * (G - mu1 * wg1[d]) + wb1[d] + bff1[d];
    __syncthreads();            // fence spart reads before GEMV-C writes
    sf[d] = fmaxf(fp, 0.f);
    __syncthreads();

    // y = r1 + wff2@f + bff2
    float yacc = gemv512(wff2T, sf, spart, tid, d);
    float y = r1 + bff2[d] + yacc;

    reduce2_512(y, y * y, tid, l16, sum, sumsq);
    float mu2 = sum * (1.f / DIM);
    float inv2 = rsqrtf(sumsq * (1.f / DIM) - mu2 * mu2 + 1e-5f);
    float h2 = (y - mu2) * inv2 * g2[d] + b2[d];

    reduce2_512(h2, h2 * h2, tid, l16, sum, sumsq);
    float mu3 = sum * (1.f / DIM);
    float inv3 = rsqrtf(sumsq * (1.f / DIM) - mu3 * mu3 + 1e-5f);
    float h3 = (h2 - mu3) * inv3 * gf[d] + bfv[d];

    float pfc = wfc[d] * h3;
    float dummy;
    reduce2_512(pfc, 0.f, tid, l16, sum, dummy);
    if (tid == 0) out[n] = sum + bfc[0];
}

extern "C" void kernel_launch(void* const* d_in, const int* in_sizes, int n_in,
                              void* d_out, int out_size, void* d_ws, size_t ws_size,
                              hipStream_t stream) {
    const float* x    = (const float*)d_in[0];
    const float* w_in = (const float*)d_in[1];
    const float* b_in = (const float*)d_in[2];
    const float* wq   = (const float*)d_in[3];
    const float* bq   = (const float*)d_in[4];
    const float* wk   = (const float*)d_in[5];
    const float* bk   = (const float*)d_in[6];
    const float* wv   = (const float*)d_in[7];
    const float* bv   = (const float*)d_in[8];
    const float* wo   = (const float*)d_in[9];
    const float* bo   = (const float*)d_in[10];
    const float* g1   = (const float*)d_in[11];
    const float* b1   = (const float*)d_in[12];
    const float* wff1 = (const float*)d_in[13];
    const float* bff1 = (const float*)d_in[14];
    const float* wff2 = (const float*)d_in[15];
    const float* bff2 = (const float*)d_in[16];
    const float* g2   = (const float*)d_in[17];
    const float* b2   = (const float*)d_in[18];
    const float* gf   = (const float*)d_in[19];
    const float* bf   = (const float*)d_in[20];
    const float* wfc  = (const float*)d_in[21];
    const float* bfc  = (const float*)d_in[22];

    char* ws = (char*)d_ws;
    float* wq2     = (float*)(ws + 0);         // 64 KiB
    float* bq2     = (float*)(ws + 65536);     // 2 KiB
    u16*   wk2b    = (u16*)  (ws + 67584);     // 32 KiB
    float* bk2     = (float*)(ws + 100352);    // 2 KiB
    float* wv2     = (float*)(ws + 102400);    // 64 KiB
    float* wvb     = (float*)(ws + 167936);    // 2 KiB
    float* bb      = (float*)(ws + 169984);    // 2 KiB
    float* wf1x    = (float*)(ws + 172032);    // 64 KiB
    float* wf1c    = (float*)(ws + 237568);    // 2 KiB
    float* wg1     = (float*)(ws + 239616);    // 2 KiB
    float* wb1     = (float*)(ws + 241664);    // 2 KiB
    u16*   woT     = (u16*)  (ws + 243712);    // 512 KiB
    u16*   wff1g1T = (u16*)  (ws + 767872);    // 512 KiB
    u16*   wff2T   = (u16*)  (ws + 1292160);   // 512 KiB
    float* xup     = (float*)(ws + 1816448);   // 64 KiB  [512][32]
    float* zdp     = (float*)(ws + 1881984);   // 2 KiB   [512]

    k_p1<<<704, 256, 0, stream>>>(x, w_in, b_in, wq, bq, wk, bk, wv, bv, wo, bo,
                                  g1, b1, wff1, wff2,
                                  wq2, bq2, wk2b, bk2, wv2, wvb,
                                  wf1x, wf1c, wg1, wb1, bb,
                                  woT, wff1g1T, wff2T);
    k_w<<<NTILE, 256, 0, stream>>>(x, wq2, bq2, wk2b, bk2, xup, zdp);
    k_final<<<NB, 512, 0, stream>>>(x, w_in, wv2, wvb, bb, wf1x, wf1c, wg1, wb1,
                                    g1, b1, bff1, bff2, woT, wff1g1T, wff2T,
                                    g2, b2, gf, bf, wfc, bfc, xup, zdp,
                                    (float*)d_out);
}